// Round 1
// baseline (182.382 us; speedup 1.0000x reference)
//
#include <hip/hip_runtime.h>
#include <math.h>

#define EPS   1e-6f
#define K_V   0.4052847345693511f   /* 4/pi^2 */
#define IMG2  369664.0f             /* 608^2 */
#define NBOX  150
#define NCLS  20

__device__ __forceinline__ float bce_logits(float x, float t) {
    // logaddexp(0,x) - x*t  (numerically stable)
    return fmaxf(x, 0.f) + log1pf(expf(-fabsf(x))) - x * t;
}

__device__ __forceinline__ float wave_sum(float v) {
#pragma unroll
    for (int off = 32; off > 0; off >>= 1) v += __shfl_down(v, off, 64);
    return v;
}

// Grid layout: blocks [0,272) -> layer0 (68 blk/batch), [272,340) -> layer1
// (17 blk/batch), [340,360) -> layer2 (5 blk/batch). 256 threads/block.
__global__ __launch_bounds__(256) void yolo_loss_kernel(
    const float* __restrict__ p0,  const float* __restrict__ pd0,
    const float* __restrict__ lb0, const float* __restrict__ bb0,
    const float* __restrict__ p1,  const float* __restrict__ pd1,
    const float* __restrict__ lb1, const float* __restrict__ bb1,
    const float* __restrict__ p2,  const float* __restrict__ pd2,
    const float* __restrict__ lb2, const float* __restrict__ bb2,
    float* __restrict__ ws)
{
    __shared__ float s_lox[NBOX], s_loy[NBOX], s_hix[NBOX], s_hiy[NBOX];
    __shared__ float s_area[NBOX], s_at[NBOX], s_cx[NBOX], s_cy[NBOX];

    const int blk = blockIdx.x;
    const float *p, *pd, *lb, *bb;
    int batch, lblk, apb;
    if (blk < 272) {
        p = p0; pd = pd0; lb = lb0; bb = bb0;
        batch = blk / 68; lblk = blk % 68; apb = 17328;       // 76*76*3
    } else if (blk < 340) {
        int r = blk - 272;
        p = p1; pd = pd1; lb = lb1; bb = bb1;
        batch = r / 17; lblk = r % 17; apb = 4332;            // 38*38*3
    } else {
        int r = blk - 340;
        p = p2; pd = pd2; lb = lb2; bb = bb2;
        batch = r / 5; lblk = r % 5; apb = 1083;              // 19*19*3
    }

    const int tid = threadIdx.x;

    // Stage this batch's 150 bboxes (derived values) into LDS.
    if (tid < NBOX) {
        const float* b = bb + (size_t)(batch * NBOX + tid) * 4;
        float bx = b[0], by = b[1], bw = b[2], bh = b[3];
        float hw = bw * 0.5f, hh = bh * 0.5f;
        float ltx = bx - hw, lty = by - hh, rbx = bx + hw, rby = by + hh;
        float lox = fminf(ltx, rbx), hix = fmaxf(ltx, rbx);
        float loy = fminf(lty, rby), hiy = fmaxf(lty, rby);
        s_lox[tid] = lox;  s_loy[tid] = loy;
        s_hix[tid] = hix;  s_hiy[tid] = hiy;
        s_area[tid] = (hix - lox) * (hiy - loy);
        s_at[tid] = atanf(bw / fmaxf(bh, EPS));
        s_cx[tid] = bx;    s_cy[tid] = by;
    }
    __syncthreads();

    const int a = lblk * 256 + tid;
    float t_ciou = 0.f, t_conf = 0.f, t_cls = 0.f;

    if (a < apb) {
        const size_t base = (size_t)batch * apb + a;
        const float* pdp = pd + base * 25;
        const float  b1x = pdp[0], b1y = pdp[1], b1w = pdp[2], b1h = pdp[3];
        const float hw = b1w * 0.5f, hh = b1h * 0.5f;
        const float l1x = b1x - hw, l1y = b1y - hh;
        const float r1x = b1x + hw, r1y = b1y + hh;
        const float lo1x = fminf(l1x, r1x), hi1x = fmaxf(l1x, r1x);
        const float lo1y = fminf(l1y, r1y), hi1y = fmaxf(l1y, r1y);
        const float area1 = (hi1x - lo1x) * (hi1y - lo1y);
        const float at1 = atanf(b1w / fmaxf(b1h, EPS));

        const float* lbp = lb + base * 26;
        const float obj = lbp[4], mix = lbp[5];
        const float pconf = p[base * 25 + 4];

        // focal confidence term (needed for both obj and noobj anchors)
        const float sig = 1.f / (1.f + expf(-pconf));
        const float dd = fabsf(obj - sig);
        const float focal = bce_logits(pconf, obj) * (dd * dd);  // ALPHA=1, GAMMA=2

        float gate;  // obj + (1-obj)*(iou_max < 0.5)
        if (obj > 0.f) {
            // ---- CIoU vs label box + class BCE (obj anchors, ~5%) ----
            const float lx = lbp[0], ly = lbp[1], lw = lbp[2], lh = lbp[3];
            const float hlw = lw * 0.5f, hlh = lh * 0.5f;
            const float l2x = lx - hlw, l2y = ly - hlh;
            const float r2x = lx + hlw, r2y = ly + hlh;
            const float lo2x = fminf(l2x, r2x), hi2x = fmaxf(l2x, r2x);
            const float lo2y = fminf(l2y, r2y), hi2y = fmaxf(l2y, r2y);
            const float area2 = (hi2x - lo2x) * (hi2y - lo2y);
            float iwx = fmaxf(fminf(hi1x, hi2x) - fmaxf(lo1x, lo2x), 0.f);
            float iwy = fmaxf(fminf(hi1y, hi2y) - fmaxf(lo1y, lo2y), 0.f);
            float inter = iwx * iwy;
            float uni = area1 + area2 - inter;
            float iou = inter / fmaxf(uni, EPS);
            float owx = fmaxf(hi1x, hi2x) - fminf(lo1x, lo2x);
            float owy = fmaxf(hi1y, hi2y) - fminf(lo1y, lo2y);
            float c2 = fmaxf(owx * owx + owy * owy, EPS);
            float dx = b1x - lx, dy = b1y - ly;
            float u = (dx * dx + dy * dy) / c2;
            float at2 = atanf(lw / fmaxf(lh, EPS));
            float dv = at2 - at1;
            float v = K_V * dv * dv;
            float alpha = v / fmaxf(1.f - iou + v, EPS);
            float ciou = iou - (u + alpha * v);

            float scale = 2.f - lw * lh * (1.f / IMG2);
            t_ciou = scale * (1.f - ciou) * mix;     // obj == 1

            float s = 0.f;
            const float* pc = p + base * 25 + 5;
            const float* lc = lbp + 6;
#pragma unroll
            for (int c = 0; c < NCLS; ++c) s += bce_logits(pc[c], lc[c]);
            t_cls = s * mix;                          // obj == 1
            gate = 1.f;
        } else {
            // ---- max CIoU vs this batch's 150 gt bboxes (noobj anchors) ----
            float best = -1e30f;
#pragma unroll 5
            for (int j = 0; j < NBOX; ++j) {
                float iwx = fminf(hi1x, s_hix[j]) - fmaxf(lo1x, s_lox[j]);
                float iwy = fminf(hi1y, s_hiy[j]) - fmaxf(lo1y, s_loy[j]);
                iwx = fmaxf(iwx, 0.f); iwy = fmaxf(iwy, 0.f);
                float inter = iwx * iwy;
                float uni = area1 + s_area[j] - inter;
                float iou = inter / fmaxf(uni, EPS);
                float owx = fmaxf(hi1x, s_hix[j]) - fminf(lo1x, s_lox[j]);
                float owy = fmaxf(hi1y, s_hiy[j]) - fminf(lo1y, s_loy[j]);
                float c2 = fmaxf(owx * owx + owy * owy, EPS);
                float dx = b1x - s_cx[j], dy = b1y - s_cy[j];
                float u = (dx * dx + dy * dy) / c2;
                float dv = s_at[j] - at1;
                float v = K_V * dv * dv;
                float alpha = v / fmaxf(1.f - iou + v, EPS);
                float ci = iou - (u + alpha * v);
                best = fmaxf(best, ci);
            }
            gate = (best < 0.5f) ? 1.f : 0.f;
        }
        t_conf = gate * focal * mix;
    }

    // block reduction: wave shuffle, then one atomicAdd per wave per channel
    float r0 = wave_sum(t_ciou);
    float r1 = wave_sum(t_conf);
    float r2 = wave_sum(t_cls);
    if ((tid & 63) == 0) {
        atomicAdd(&ws[0], r0);
        atomicAdd(&ws[1], r1);
        atomicAdd(&ws[2], r2);
    }
}

__global__ void yolo_finalize_kernel(const float* __restrict__ ws,
                                     float* __restrict__ out)
{
    if (threadIdx.x == 0) {
        float c = ws[0], f = ws[1], cl = ws[2];
        const float inv_bs = 0.25f;   // bs = 4 for every layer
        out[0] = (c + f + cl) * inv_bs;
        out[1] = c * inv_bs;
        out[2] = f * inv_bs;
        out[3] = cl * inv_bs;
    }
}

extern "C" void kernel_launch(void* const* d_in, const int* in_sizes, int n_in,
                              void* d_out, int out_size, void* d_ws, size_t ws_size,
                              hipStream_t stream) {
    // setup_inputs() dict order: p0, p_d0, label0, bboxes0, p1, p_d1, label1,
    // bboxes1, p2, p_d2, label2, bboxes2
    const float* p0  = (const float*)d_in[0];
    const float* pd0 = (const float*)d_in[1];
    const float* lb0 = (const float*)d_in[2];
    const float* bb0 = (const float*)d_in[3];
    const float* p1  = (const float*)d_in[4];
    const float* pd1 = (const float*)d_in[5];
    const float* lb1 = (const float*)d_in[6];
    const float* bb1 = (const float*)d_in[7];
    const float* p2  = (const float*)d_in[8];
    const float* pd2 = (const float*)d_in[9];
    const float* lb2 = (const float*)d_in[10];
    const float* bb2 = (const float*)d_in[11];

    float* ws = (float*)d_ws;
    hipMemsetAsync(ws, 0, 3 * sizeof(float), stream);

    yolo_loss_kernel<<<360, 256, 0, stream>>>(
        p0, pd0, lb0, bb0, p1, pd1, lb1, bb1, p2, pd2, lb2, bb2, ws);

    yolo_finalize_kernel<<<1, 64, 0, stream>>>(ws, (float*)d_out);
}

// Round 2
// 168.897 us; speedup vs baseline: 1.0798x; 1.0798x over previous
//
#include <hip/hip_runtime.h>
#include <math.h>

#define EPS   1e-6f
#define K_V   0.4052847345693511f   /* 4/pi^2 */
#define IMG2  369664.0f             /* 608^2 */
#define NBOX  150
#define NCLS  20
#define NBLK  360

__device__ __forceinline__ float bce_logits(float x, float t) {
    // logaddexp(0,x) - x*t  (numerically stable)
    return fmaxf(x, 0.f) + log1pf(expf(-fabsf(x))) - x * t;
}

__device__ __forceinline__ float wave_sum(float v) {
#pragma unroll
    for (int off = 32; off > 0; off >>= 1) v += __shfl_down(v, off, 64);
    return v;
}

// Grid layout: blocks [0,272) -> layer0 (68 blk/batch), [272,340) -> layer1
// (17 blk/batch), [340,360) -> layer2 (5 blk/batch). 256 threads/block.
__global__ __launch_bounds__(256) void yolo_loss_kernel(
    const float* __restrict__ p0,  const float* __restrict__ pd0,
    const float* __restrict__ lb0, const float* __restrict__ bb0,
    const float* __restrict__ p1,  const float* __restrict__ pd1,
    const float* __restrict__ lb1, const float* __restrict__ bb1,
    const float* __restrict__ p2,  const float* __restrict__ pd2,
    const float* __restrict__ lb2, const float* __restrict__ bb2,
    float* __restrict__ ws, float* __restrict__ out)
{
    __shared__ float4 s_box[NBOX];   // lox, loy, hix, hiy
    __shared__ float  s_area[NBOX], s_at[NBOX], s_cx[NBOX], s_cy[NBOX];

    const int blk = blockIdx.x;
    const float *p, *pd, *lb, *bb;
    int batch, lblk, apb;
    if (blk < 272) {
        p = p0; pd = pd0; lb = lb0; bb = bb0;
        batch = blk / 68; lblk = blk % 68; apb = 17328;       // 76*76*3
    } else if (blk < 340) {
        int r = blk - 272;
        p = p1; pd = pd1; lb = lb1; bb = bb1;
        batch = r / 17; lblk = r % 17; apb = 4332;            // 38*38*3
    } else {
        int r = blk - 340;
        p = p2; pd = pd2; lb = lb2; bb = bb2;
        batch = r / 5; lblk = r % 5; apb = 1083;              // 19*19*3
    }

    const int tid = threadIdx.x;
    const int a = lblk * 256 + tid;
    const bool active = (a < apb);
    const size_t base = (size_t)batch * apb + a;

    // Issue per-anchor global loads early so latency overlaps LDS staging.
    float b1x = 0.f, b1y = 0.f, b1w = 0.f, b1h = 0.f;
    float obj = 0.f, mix = 0.f, pconf = 0.f;
    const float* lbp = lb + base * 26;
    if (active) {
        const float* pdp = pd + base * 25;
        b1x = pdp[0]; b1y = pdp[1]; b1w = pdp[2]; b1h = pdp[3];
        float2 om = *(const float2*)(lbp + 4);   // 104B row stride -> 8B aligned
        obj = om.x; mix = om.y;
        pconf = p[base * 25 + 4];
    }

    // Stage this batch's 150 bboxes (derived values) into LDS.
    if (tid < NBOX) {
        const float* b = bb + (size_t)(batch * NBOX + tid) * 4;
        float bx = b[0], by = b[1], bw = b[2], bh = b[3];
        float hw = bw * 0.5f, hh = bh * 0.5f;
        float ltx = bx - hw, lty = by - hh, rbx = bx + hw, rby = by + hh;
        float lox = fminf(ltx, rbx), hix = fmaxf(ltx, rbx);
        float loy = fminf(lty, rby), hiy = fmaxf(lty, rby);
        s_box[tid]  = make_float4(lox, loy, hix, hiy);
        s_area[tid] = (hix - lox) * (hiy - loy);
        s_at[tid]   = atanf(bw / fmaxf(bh, EPS));
        s_cx[tid]   = bx;  s_cy[tid] = by;
    }
    __syncthreads();

    float t_ciou = 0.f, t_conf = 0.f, t_cls = 0.f;

    if (active) {
        const float hw = b1w * 0.5f, hh = b1h * 0.5f;
        const float l1x = b1x - hw, l1y = b1y - hh;
        const float r1x = b1x + hw, r1y = b1y + hh;
        const float lo1x = fminf(l1x, r1x), hi1x = fmaxf(l1x, r1x);
        const float lo1y = fminf(l1y, r1y), hi1y = fmaxf(l1y, r1y);
        const float area1 = (hi1x - lo1x) * (hi1y - lo1y);

        // focal confidence term (needed for both obj and noobj anchors)
        const float sig = 1.f / (1.f + expf(-pconf));
        const float dd = fabsf(obj - sig);
        const float focal = bce_logits(pconf, obj) * (dd * dd);  // ALPHA=1, GAMMA=2

        float gate;  // obj + (1-obj)*(iou_max < 0.5)
        if (obj > 0.f) {
            // ---- CIoU vs label box + class BCE (obj anchors, ~5%) ----
            const float at1 = atanf(b1w / fmaxf(b1h, EPS));
            const float lx = lbp[0], ly = lbp[1], lw = lbp[2], lh = lbp[3];
            const float hlw = lw * 0.5f, hlh = lh * 0.5f;
            const float l2x = lx - hlw, l2y = ly - hlh;
            const float r2x = lx + hlw, r2y = ly + hlh;
            const float lo2x = fminf(l2x, r2x), hi2x = fmaxf(l2x, r2x);
            const float lo2y = fminf(l2y, r2y), hi2y = fmaxf(l2y, r2y);
            const float area2 = (hi2x - lo2x) * (hi2y - lo2y);
            float iwx = fmaxf(fminf(hi1x, hi2x) - fmaxf(lo1x, lo2x), 0.f);
            float iwy = fmaxf(fminf(hi1y, hi2y) - fmaxf(lo1y, lo2y), 0.f);
            float inter = iwx * iwy;
            float uni = area1 + area2 - inter;
            float iou = inter / fmaxf(uni, EPS);
            float owx = fmaxf(hi1x, hi2x) - fminf(lo1x, lo2x);
            float owy = fmaxf(hi1y, hi2y) - fminf(lo1y, lo2y);
            float c2 = fmaxf(owx * owx + owy * owy, EPS);
            float dx = b1x - lx, dy = b1y - ly;
            float u = (dx * dx + dy * dy) / c2;
            float at2 = atanf(lw / fmaxf(lh, EPS));
            float dv = at2 - at1;
            float v = K_V * dv * dv;
            float alpha = v / fmaxf(1.f - iou + v, EPS);
            float ciou = iou - (u + alpha * v);

            float scale = 2.f - lw * lh * (1.f / IMG2);
            t_ciou = scale * (1.f - ciou) * mix;     // obj == 1

            float s = 0.f;
            const float* pc = p + base * 25 + 5;
            const float* lc = lbp + 6;
#pragma unroll
            for (int c = 0; c < NCLS; ++c) s += bce_logits(pc[c], lc[c]);
            t_cls = s * mix;                          // obj == 1
            gate = 1.f;
        } else {
            // ---- gate = (max_j ciou_j < 0.5). Since ciou <= iou, only boxes
            // with iou >= 0.5 can trip the gate, and iou >= 0.5 is a
            // division-free test: 2*inter >= max(union, EPS). Pre-test with
            // 0.999 slack (covers div rounding), exact CIoU on the rare hits.
            const float at1 = atanf(b1w / fmaxf(b1h, EPS));
            bool hit = false;
#pragma unroll 5
            for (int j = 0; j < NBOX; ++j) {
                float4 b4 = s_box[j];
                float ix0 = fmaxf(lo1x, b4.x), iy0 = fmaxf(lo1y, b4.y);
                float ix1 = fminf(hi1x, b4.z), iy1 = fminf(hi1y, b4.w);
                float iwx = fmaxf(ix1 - ix0, 0.f);
                float iwy = fmaxf(iy1 - iy0, 0.f);
                float inter = iwx * iwy;
                float uni_m = fmaxf(area1 + s_area[j] - inter, EPS);
                if (inter + inter >= uni_m * 0.999f) {
                    float iou = inter / uni_m;
                    float owx = fmaxf(hi1x, b4.z) - fminf(lo1x, b4.x);
                    float owy = fmaxf(hi1y, b4.w) - fminf(lo1y, b4.y);
                    float c2 = fmaxf(owx * owx + owy * owy, EPS);
                    float dx = b1x - s_cx[j], dy = b1y - s_cy[j];
                    float u = (dx * dx + dy * dy) / c2;
                    float dv = s_at[j] - at1;
                    float v = K_V * dv * dv;
                    float alpha = v / fmaxf(1.f - iou + v, EPS);
                    float ci = iou - (u + alpha * v);
                    hit = hit || (ci >= 0.5f);
                }
            }
            gate = hit ? 0.f : 1.f;
        }
        t_conf = gate * focal * mix;
    }

    // block reduction: wave shuffle, then one atomicAdd per wave per channel
    float r0 = wave_sum(t_ciou);
    float r1 = wave_sum(t_conf);
    float r2 = wave_sum(t_cls);
    if ((tid & 63) == 0) {
        atomicAdd(&ws[0], r0);
        atomicAdd(&ws[1], r1);
        atomicAdd(&ws[2], r2);
    }

    // last-block-done finalize (saves a separate dispatch)
    __syncthreads();
    if (tid == 0) {
        __threadfence();
        unsigned old = atomicAdd((unsigned*)(ws + 3), 1u);
        if (old == NBLK - 1) {
            float c  = atomicAdd(&ws[0], 0.f);   // atomic reads: device-coherent
            float f  = atomicAdd(&ws[1], 0.f);
            float cl = atomicAdd(&ws[2], 0.f);
            const float inv_bs = 0.25f;          // bs = 4 for every layer
            out[0] = (c + f + cl) * inv_bs;
            out[1] = c * inv_bs;
            out[2] = f * inv_bs;
            out[3] = cl * inv_bs;
        }
    }
}

extern "C" void kernel_launch(void* const* d_in, const int* in_sizes, int n_in,
                              void* d_out, int out_size, void* d_ws, size_t ws_size,
                              hipStream_t stream) {
    // setup_inputs() dict order: p0, p_d0, label0, bboxes0, p1, p_d1, label1,
    // bboxes1, p2, p_d2, label2, bboxes2
    const float* p0  = (const float*)d_in[0];
    const float* pd0 = (const float*)d_in[1];
    const float* lb0 = (const float*)d_in[2];
    const float* bb0 = (const float*)d_in[3];
    const float* p1  = (const float*)d_in[4];
    const float* pd1 = (const float*)d_in[5];
    const float* lb1 = (const float*)d_in[6];
    const float* bb1 = (const float*)d_in[7];
    const float* p2  = (const float*)d_in[8];
    const float* pd2 = (const float*)d_in[9];
    const float* lb2 = (const float*)d_in[10];
    const float* bb2 = (const float*)d_in[11];

    float* ws = (float*)d_ws;
    hipMemsetAsync(ws, 0, 4 * sizeof(float), stream);   // 3 accumulators + counter

    yolo_loss_kernel<<<NBLK, 256, 0, stream>>>(
        p0, pd0, lb0, bb0, p1, pd1, lb1, bb1, p2, pd2, lb2, bb2,
        ws, (float*)d_out);
}

// Round 3
// 158.713 us; speedup vs baseline: 1.1491x; 1.0642x over previous
//
#include <hip/hip_runtime.h>
#include <math.h>

#define EPS   1e-6f
#define K_V   0.4052847345693511f   /* 4/pi^2 */
#define IMG2  369664.0f             /* 608^2 */
#define NBOX  150
#define NCLS  20

// 128 anchors per block, 2 lanes per anchor (half 0: boxes 0-74, half 1: 75-149)
#define BLK_L0 136   /* ceil(17328/128) */
#define BLK_L1 34    /* ceil(4332/128)  */
#define BLK_L2 9     /* ceil(1083/128)  */
#define NBLK   (4*(BLK_L0+BLK_L1+BLK_L2))   /* 716 */

__device__ __forceinline__ float bce_logits(float x, float t) {
    return fmaxf(x, 0.f) + log1pf(expf(-fabsf(x))) - x * t;
}

__device__ __forceinline__ float wave_sum(float v) {
#pragma unroll
    for (int off = 32; off > 0; off >>= 1) v += __shfl_down(v, off, 64);
    return v;
}

__global__ __launch_bounds__(256, 4) void yolo_loss_kernel(
    const float* __restrict__ p0,  const float* __restrict__ pd0,
    const float* __restrict__ lb0, const float* __restrict__ bb0,
    const float* __restrict__ p1,  const float* __restrict__ pd1,
    const float* __restrict__ lb1, const float* __restrict__ bb1,
    const float* __restrict__ p2,  const float* __restrict__ pd2,
    const float* __restrict__ lb2, const float* __restrict__ bb2,
    float* __restrict__ ws, float* __restrict__ out)
{
    __shared__ float4 s_box[NBOX];                 // lox, loy, hix, hiy
    __shared__ float  s_area[NBOX], s_at[NBOX], s_cx[NBOX], s_cy[NBOX];
    __shared__ float  s_part[4][3];

    const int blk = blockIdx.x;
    const float *p, *pd, *lb, *bb;
    int batch, lblk, apb;
    if (blk < 4*BLK_L0) {
        p = p0; pd = pd0; lb = lb0; bb = bb0;
        batch = blk / BLK_L0; lblk = blk % BLK_L0; apb = 17328;
    } else if (blk < 4*(BLK_L0+BLK_L1)) {
        int r = blk - 4*BLK_L0;
        p = p1; pd = pd1; lb = lb1; bb = bb1;
        batch = r / BLK_L1; lblk = r % BLK_L1; apb = 4332;
    } else {
        int r = blk - 4*(BLK_L0+BLK_L1);
        p = p2; pd = pd2; lb = lb2; bb = bb2;
        batch = r / BLK_L2; lblk = r % BLK_L2; apb = 1083;
    }

    const int tid  = threadIdx.x;
    const int wave = tid >> 6, lane = tid & 63;
    const int half = lane >> 5, sub = lane & 31;
    const int a = lblk * 128 + wave * 32 + sub;
    const bool active = (a < apb);
    const size_t base = (size_t)batch * apb + a;
    const float* lbp = lb + base * 26;

    // per-anchor global loads issued early (overlap with LDS staging)
    float b1x = 0.f, b1y = 0.f, b1w = 1.f, b1h = 1.f;
    float obj = 0.f, mix = 0.f, pconf = 0.f;
    if (active) {
        const float* pdp = pd + base * 25;
        b1x = pdp[0]; b1y = pdp[1]; b1w = pdp[2]; b1h = pdp[3];
        float2 om = *(const float2*)(lbp + 4);   // 104B row stride -> 8B aligned
        obj = om.x; mix = om.y;
        pconf = p[base * 25 + 4];
    }

    // stage this batch's 150 bboxes (derived values) into LDS
    if (tid < NBOX) {
        float4 b = ((const float4*)bb)[batch * NBOX + tid];  // 16B aligned
        float hw = b.z * 0.5f, hh = b.w * 0.5f;
        float ltx = b.x - hw, lty = b.y - hh, rbx = b.x + hw, rby = b.y + hh;
        float lox = fminf(ltx, rbx), hix = fmaxf(ltx, rbx);
        float loy = fminf(lty, rby), hiy = fmaxf(lty, rby);
        s_box[tid]  = make_float4(lox, loy, hix, hiy);
        s_area[tid] = (hix - lox) * (hiy - loy);
        s_at[tid]   = atanf(b.z / fmaxf(b.w, EPS));
        s_cx[tid]   = b.x;  s_cy[tid] = b.y;
    }
    __syncthreads();

    float t_ciou = 0.f, t_conf = 0.f, t_cls = 0.f;

    float lo1x = 0.f, lo1y = 0.f, hi1x = 0.f, hi1y = 0.f, area1 = 0.f;
    if (active) {
        const float hw = b1w * 0.5f, hh = b1h * 0.5f;
        const float l1x = b1x - hw, l1y = b1y - hh;
        const float r1x = b1x + hw, r1y = b1y + hh;
        lo1x = fminf(l1x, r1x); hi1x = fmaxf(l1x, r1x);
        lo1y = fminf(l1y, r1y); hi1y = fmaxf(l1y, r1y);
        area1 = (hi1x - lo1x) * (hi1y - lo1y);
    }

    // ---- phase 1: branch-free division-free pre-test over this half's boxes.
    // metric = 2*inter - 0.999*max(union,EPS) > 0  is necessary for iou>=0.5
    // (ciou <= iou always), with 0.999 slack covering division rounding.
    const int j0 = half * 75;
    float best = -1.f;
    if (active && obj == 0.f) {
#pragma unroll 5
        for (int j = j0; j < j0 + 75; ++j) {
            float4 b4 = s_box[j];
            float a2  = s_area[j];
            float ix0 = fmaxf(lo1x, b4.x), iy0 = fmaxf(lo1y, b4.y);
            float ix1 = fminf(hi1x, b4.z), iy1 = fminf(hi1y, b4.w);
            float iwx = fmaxf(ix1 - ix0, 0.f);
            float iwy = fmaxf(iy1 - iy0, 0.f);
            float inter = iwx * iwy;
            float uni_m = fmaxf(area1 + a2 - inter, EPS);
            float metric = fmaf(-0.999f, uni_m, inter + inter);
            best = fmaxf(best, metric);
        }
    }

    // ---- phase 2 (rare): exact ciou >= 0.5 check for flagged lanes
    int hit = 0;
    const bool need = active && (obj == 0.f) && (best > 0.f);
    if (__any((int)need)) {
        if (need) {
            float at1 = atanf(b1w / fmaxf(b1h, EPS));
            for (int j = j0; j < j0 + 75; ++j) {
                float4 b4 = s_box[j];
                float ix0 = fmaxf(lo1x, b4.x), iy0 = fmaxf(lo1y, b4.y);
                float ix1 = fminf(hi1x, b4.z), iy1 = fminf(hi1y, b4.w);
                float iwx = fmaxf(ix1 - ix0, 0.f);
                float iwy = fmaxf(iy1 - iy0, 0.f);
                float inter = iwx * iwy;
                float uni_m = fmaxf(area1 + s_area[j] - inter, EPS);
                float iou = inter / uni_m;
                float owx = fmaxf(hi1x, b4.z) - fminf(lo1x, b4.x);
                float owy = fmaxf(hi1y, b4.w) - fminf(lo1y, b4.y);
                float c2 = fmaxf(owx * owx + owy * owy, EPS);
                float dx = b1x - s_cx[j], dy = b1y - s_cy[j];
                float u = (dx * dx + dy * dy) / c2;
                float dv = s_at[j] - at1;
                float v = K_V * dv * dv;
                float alpha = v / fmaxf(1.f - iou + v, EPS);
                float ci = iou - (u + alpha * v);
                hit |= (ci >= 0.5f);
            }
        }
    }
    hit |= __shfl_xor(hit, 32, 64);   // combine box halves for this anchor

    // ---- per-anchor outputs, computed by half 0 only
    if (active && half == 0) {
        const float sig = 1.f / (1.f + expf(-pconf));
        const float dd = fabsf(obj - sig);
        const float focal = bce_logits(pconf, obj) * (dd * dd); // ALPHA=1,GAMMA=2
        float gate;
        if (obj > 0.f) {
            const float at1 = atanf(b1w / fmaxf(b1h, EPS));
            const float lx = lbp[0], ly = lbp[1], lw = lbp[2], lh = lbp[3];
            const float hlw = lw * 0.5f, hlh = lh * 0.5f;
            const float l2x = lx - hlw, l2y = ly - hlh;
            const float r2x = lx + hlw, r2y = ly + hlh;
            const float lo2x = fminf(l2x, r2x), hi2x = fmaxf(l2x, r2x);
            const float lo2y = fminf(l2y, r2y), hi2y = fmaxf(l2y, r2y);
            const float area2 = (hi2x - lo2x) * (hi2y - lo2y);
            float iwx = fmaxf(fminf(hi1x, hi2x) - fmaxf(lo1x, lo2x), 0.f);
            float iwy = fmaxf(fminf(hi1y, hi2y) - fmaxf(lo1y, lo2y), 0.f);
            float inter = iwx * iwy;
            float uni = area1 + area2 - inter;
            float iou = inter / fmaxf(uni, EPS);
            float owx = fmaxf(hi1x, hi2x) - fminf(lo1x, lo2x);
            float owy = fmaxf(hi1y, hi2y) - fminf(lo1y, lo2y);
            float c2 = fmaxf(owx * owx + owy * owy, EPS);
            float dx = b1x - lx, dy = b1y - ly;
            float u = (dx * dx + dy * dy) / c2;
            float at2 = atanf(lw / fmaxf(lh, EPS));
            float dv = at2 - at1;
            float v = K_V * dv * dv;
            float alpha = v / fmaxf(1.f - iou + v, EPS);
            float ciou = iou - (u + alpha * v);

            float scale = 2.f - lw * lh * (1.f / IMG2);
            t_ciou = scale * (1.f - ciou) * mix;

            float s = 0.f;
            const float* pc = p + base * 25 + 5;
            const float* lc = lbp + 6;
#pragma unroll
            for (int c = 0; c < NCLS; ++c) s += bce_logits(pc[c], lc[c]);
            t_cls = s * mix;
            gate = 1.f;
        } else {
            gate = hit ? 0.f : 1.f;
        }
        t_conf = gate * focal * mix;
    }

    // ---- block reduction: wave shuffle -> LDS -> 3 atomics per block
    float r0 = wave_sum(t_ciou);
    float r1 = wave_sum(t_conf);
    float r2 = wave_sum(t_cls);
    if (lane == 0) { s_part[wave][0] = r0; s_part[wave][1] = r1; s_part[wave][2] = r2; }
    __syncthreads();

    if (tid == 0) {
        float c = 0.f, f = 0.f, cl = 0.f;
#pragma unroll
        for (int w = 0; w < 4; ++w) { c += s_part[w][0]; f += s_part[w][1]; cl += s_part[w][2]; }
        const int slot = (blk & 7) * 16;      // 8 XCD-strided slots, 64B apart
        atomicAdd(&ws[slot + 0], c);
        atomicAdd(&ws[slot + 1], f);
        atomicAdd(&ws[slot + 2], cl);
        __threadfence();
        unsigned old = atomicAdd((unsigned*)(ws + 128), 1u);
        if (old == NBLK - 1) {
            __threadfence();
            float C = 0.f, F = 0.f, CL = 0.f;
#pragma unroll
            for (int s = 0; s < 8; ++s) {
                C  += atomicAdd(&ws[s*16 + 0], 0.f);   // coherent L2 reads
                F  += atomicAdd(&ws[s*16 + 1], 0.f);
                CL += atomicAdd(&ws[s*16 + 2], 0.f);
            }
            const float inv_bs = 0.25f;   // bs = 4 for every layer
            out[0] = (C + F + CL) * inv_bs;
            out[1] = C * inv_bs;
            out[2] = F * inv_bs;
            out[3] = CL * inv_bs;
        }
    }
}

extern "C" void kernel_launch(void* const* d_in, const int* in_sizes, int n_in,
                              void* d_out, int out_size, void* d_ws, size_t ws_size,
                              hipStream_t stream) {
    const float* p0  = (const float*)d_in[0];
    const float* pd0 = (const float*)d_in[1];
    const float* lb0 = (const float*)d_in[2];
    const float* bb0 = (const float*)d_in[3];
    const float* p1  = (const float*)d_in[4];
    const float* pd1 = (const float*)d_in[5];
    const float* lb1 = (const float*)d_in[6];
    const float* bb1 = (const float*)d_in[7];
    const float* p2  = (const float*)d_in[8];
    const float* pd2 = (const float*)d_in[9];
    const float* lb2 = (const float*)d_in[10];
    const float* bb2 = (const float*)d_in[11];

    float* ws = (float*)d_ws;
    hipMemsetAsync(ws, 0, 132 * sizeof(float), stream);  // 8 slots + counter

    yolo_loss_kernel<<<NBLK, 256, 0, stream>>>(
        p0, pd0, lb0, bb0, p1, pd1, lb1, bb1, p2, pd2, lb2, bb2,
        ws, (float*)d_out);
}

// Round 4
// 124.895 us; speedup vs baseline: 1.4603x; 1.2708x over previous
//
#include <hip/hip_runtime.h>
#include <math.h>

#define EPS   1e-6f
#define K_V   0.4052847345693511f   /* 4/pi^2 */
#define IMG2  369664.0f             /* 608^2 */
#define NBOX  150
#define NBOXP 152                   /* padded so each quarter is exactly 38 */
#define NCLS  20

// 64 anchors per block, 4 lanes per anchor (quarter q scans boxes q*38..q*38+37)
#define BPB_L0 271   /* ceil(17328/64) */
#define BPB_L1 68    /* ceil(4332/64)  */
#define BPB_L2 17    /* ceil(1083/64)  */
#define NBLK   (4*(BPB_L0+BPB_L1+BPB_L2))   /* 1424 */

__device__ __forceinline__ float fast_rcp(float x) { return __builtin_amdgcn_rcpf(x); }

__device__ __forceinline__ float bce_logits(float x, float t) {
    // logaddexp(0,x) - x*t via hw exp/log; |err| ~1e-7*|val|, threshold is 591.
    float e = __expf(-fabsf(x));
    return fmaxf(x, 0.f) + __logf(1.f + e) - x * t;
}

__device__ __forceinline__ float wave_sum(float v) {
#pragma unroll
    for (int off = 32; off > 0; off >>= 1) v += __shfl_down(v, off, 64);
    return v;
}

__global__ __launch_bounds__(256, 6) void yolo_loss_kernel(
    const float* __restrict__ p0,  const float* __restrict__ pd0,
    const float* __restrict__ lb0, const float* __restrict__ bb0,
    const float* __restrict__ p1,  const float* __restrict__ pd1,
    const float* __restrict__ lb1, const float* __restrict__ bb1,
    const float* __restrict__ p2,  const float* __restrict__ pd2,
    const float* __restrict__ lb2, const float* __restrict__ bb2,
    float* __restrict__ ws, float* __restrict__ out)
{
    __shared__ float4 s_box[NBOXP];   // lox, loy, hix, hiy
    __shared__ float4 s_aux[NBOXP];   // area, cx, cy, atan(w/h)
    __shared__ float  s_part[4][3];

    const int blk = blockIdx.x;
    const float *p, *pd, *lb, *bb;
    int batch, lblk, apb;
    if (blk < 4*BPB_L0) {
        p = p0; pd = pd0; lb = lb0; bb = bb0;
        batch = blk / BPB_L0; lblk = blk % BPB_L0; apb = 17328;
    } else if (blk < 4*(BPB_L0+BPB_L1)) {
        int r = blk - 4*BPB_L0;
        p = p1; pd = pd1; lb = lb1; bb = bb1;
        batch = r / BPB_L1; lblk = r % BPB_L1; apb = 4332;
    } else {
        int r = blk - 4*(BPB_L0+BPB_L1);
        p = p2; pd = pd2; lb = lb2; bb = bb2;
        batch = r / BPB_L2; lblk = r % BPB_L2; apb = 1083;
    }

    const int tid  = threadIdx.x;
    const int wave = tid >> 6, lane = tid & 63;
    const int q = lane >> 4, s = lane & 15;          // 4 lanes per anchor
    const int a = lblk * 64 + wave * 16 + s;
    const bool active = (a < apb);
    const size_t base = (size_t)batch * apb + a;
    const float* lbp = lb + base * 26;

    // per-anchor global loads issued early (latency overlaps LDS staging)
    float b1x = 0.f, b1y = 0.f, b1w = 1.f, b1h = 1.f;
    float obj = 0.f, mix = 0.f, pconf = 0.f;
    if (active) {
        const float* pdp = pd + base * 25;
        b1x = pdp[0]; b1y = pdp[1]; b1w = pdp[2]; b1h = pdp[3];
        float2 om = *(const float2*)(lbp + 4);   // 104B row stride -> 8B aligned
        obj = om.x; mix = om.y;
        pconf = p[base * 25 + 4];
    }

    // stage this batch's 150 bboxes (+2 degenerate pads) into LDS
    if (tid < NBOXP) {
        float bx, by, bw, bh;
        if (tid < NBOX) {
            float4 b = ((const float4*)bb)[batch * NBOX + tid];  // 16B aligned
            bx = b.x; by = b.y; bw = b.z; bh = b.w;
        } else {
            bx = 3.0e30f; by = 3.0e30f; bw = 0.f; bh = 1.f;  // never flags
        }
        float hw = bw * 0.5f, hh = bh * 0.5f;
        float ltx = bx - hw, lty = by - hh, rbx = bx + hw, rby = by + hh;
        float lox = fminf(ltx, rbx), hix = fmaxf(ltx, rbx);
        float loy = fminf(lty, rby), hiy = fmaxf(lty, rby);
        s_box[tid] = make_float4(lox, loy, hix, hiy);
        s_aux[tid] = make_float4((hix - lox) * (hiy - loy), bx, by,
                                 atanf(bw / fmaxf(bh, EPS)));
    }
    __syncthreads();

    float lo1x = 0.f, lo1y = 0.f, hi1x = 0.f, hi1y = 0.f, area1 = 0.f;
    {
        const float hw = b1w * 0.5f, hh = b1h * 0.5f;
        const float l1x = b1x - hw, l1y = b1y - hh;
        const float r1x = b1x + hw, r1y = b1y + hh;
        lo1x = fminf(l1x, r1x); hi1x = fmaxf(l1x, r1x);
        lo1y = fminf(l1y, r1y); hi1y = fmaxf(l1y, r1y);
        area1 = (hi1x - lo1x) * (hi1y - lo1y);
    }

    // ---- phase 1: division-free pre-test over this quarter's 38 boxes.
    // 2*inter >= (1-4e-6)*max(union,EPS) is necessary for fl(inter/union)>=0.5
    // (and ciou <= iou always). Flagged pairs recorded in a per-lane bitmask.
    const int j0 = q * 38;
    unsigned long long mask = 0ull;
    if (active && obj == 0.f) {
#pragma unroll 4
        for (int k = 0; k < 38; ++k) {
            float4 b4 = s_box[j0 + k];
            float a2  = s_aux[j0 + k].x;
            float ix0 = fmaxf(lo1x, b4.x), iy0 = fmaxf(lo1y, b4.y);
            float ix1 = fminf(hi1x, b4.z), iy1 = fminf(hi1y, b4.w);
            float iwx = fmaxf(ix1 - ix0, 0.f);
            float iwy = fmaxf(iy1 - iy0, 0.f);
            float inter = iwx * iwy;
            float uni_m = fmaxf(area1 + a2 - inter, EPS);
            float metric = fmaf(-0.999996f, uni_m, inter + inter);
            mask |= (unsigned long long)(metric > 0.f) << k;
        }
    }

    // ---- phase 2: exact ciou >= 0.5 only for flagged pairs (rare)
    int hit = 0;
    if (mask) {
        const float at1 = atanf(b1w / fmaxf(b1h, EPS));
        unsigned long long m = mask;
        do {
            int k = __ffsll(m) - 1; m &= m - 1;
            float4 b4 = s_box[j0 + k];
            float4 ax = s_aux[j0 + k];
            float ix0 = fmaxf(lo1x, b4.x), iy0 = fmaxf(lo1y, b4.y);
            float ix1 = fminf(hi1x, b4.z), iy1 = fminf(hi1y, b4.w);
            float iwx = fmaxf(ix1 - ix0, 0.f);
            float iwy = fmaxf(iy1 - iy0, 0.f);
            float inter = iwx * iwy;
            float iou = inter * fast_rcp(fmaxf(area1 + ax.x - inter, EPS));
            float owx = fmaxf(hi1x, b4.z) - fminf(lo1x, b4.x);
            float owy = fmaxf(hi1y, b4.w) - fminf(lo1y, b4.y);
            float c2 = fmaxf(owx * owx + owy * owy, EPS);
            float dx = b1x - ax.y, dy = b1y - ax.z;
            float u = (dx * dx + dy * dy) * fast_rcp(c2);
            float dv = ax.w - at1;
            float v = K_V * dv * dv;
            float alpha = v * fast_rcp(fmaxf(1.f - iou + v, EPS));
            float ci = iou - (u + alpha * v);
            hit |= (ci >= 0.5f);
        } while (m);
    }
    hit |= __shfl_xor(hit, 16, 64);   // combine the 4 box quarters
    hit |= __shfl_xor(hit, 32, 64);

    // ---- per-anchor outputs, computed by quarter-0 lanes only
    float t_ciou = 0.f, t_conf = 0.f, t_cls = 0.f;
    if (active && q == 0) {
        const float sig = fast_rcp(1.f + __expf(-pconf));
        const float dd = fabsf(obj - sig);
        const float focal = bce_logits(pconf, obj) * (dd * dd); // ALPHA=1,GAMMA=2
        float gate;
        if (obj > 0.f) {
            const float at1 = atanf(b1w / fmaxf(b1h, EPS));
            float2 lxy = *(const float2*)(lbp + 0);   // 8B aligned
            float2 lwh = *(const float2*)(lbp + 2);
            const float lx = lxy.x, ly = lxy.y, lw = lwh.x, lh = lwh.y;
            const float hlw = lw * 0.5f, hlh = lh * 0.5f;
            const float l2x = lx - hlw, l2y = ly - hlh;
            const float r2x = lx + hlw, r2y = ly + hlh;
            const float lo2x = fminf(l2x, r2x), hi2x = fmaxf(l2x, r2x);
            const float lo2y = fminf(l2y, r2y), hi2y = fmaxf(l2y, r2y);
            const float area2 = (hi2x - lo2x) * (hi2y - lo2y);
            float iwx = fmaxf(fminf(hi1x, hi2x) - fmaxf(lo1x, lo2x), 0.f);
            float iwy = fmaxf(fminf(hi1y, hi2y) - fmaxf(lo1y, lo2y), 0.f);
            float inter = iwx * iwy;
            float iou = inter * fast_rcp(fmaxf(area1 + area2 - inter, EPS));
            float owx = fmaxf(hi1x, hi2x) - fminf(lo1x, lo2x);
            float owy = fmaxf(hi1y, hi2y) - fminf(lo1y, lo2y);
            float c2 = fmaxf(owx * owx + owy * owy, EPS);
            float dx = b1x - lx, dy = b1y - ly;
            float u = (dx * dx + dy * dy) * fast_rcp(c2);
            float at2 = atanf(lw / fmaxf(lh, EPS));
            float dv = at2 - at1;
            float v = K_V * dv * dv;
            float alpha = v * fast_rcp(fmaxf(1.f - iou + v, EPS));
            float ciou = iou - (u + alpha * v);

            float scale = 2.f - lw * lh * (1.f / IMG2);
            t_ciou = scale * (1.f - ciou) * mix;

            float cs = 0.f;
            const float* pc = p + base * 25 + 5;
            const float* lc = lbp + 6;
#pragma unroll
            for (int c = 0; c < NCLS; ++c) cs += bce_logits(pc[c], lc[c]);
            t_cls = cs * mix;
            gate = 1.f;
        } else {
            gate = hit ? 0.f : 1.f;
        }
        t_conf = gate * focal * mix;
    }

    // ---- block reduction: wave shuffle -> LDS -> 3 atomics per block
    float r0 = wave_sum(t_ciou);
    float r1 = wave_sum(t_conf);
    float r2 = wave_sum(t_cls);
    if (lane == 0) { s_part[wave][0] = r0; s_part[wave][1] = r1; s_part[wave][2] = r2; }
    __syncthreads();

    if (tid == 0) {
        float c = 0.f, f = 0.f, cl = 0.f;
#pragma unroll
        for (int w = 0; w < 4; ++w) { c += s_part[w][0]; f += s_part[w][1]; cl += s_part[w][2]; }
        const int slot = (blk & 7) * 16;      // 8 XCD-strided slots, 64B apart
        atomicAdd(&ws[slot + 0], c);
        atomicAdd(&ws[slot + 1], f);
        atomicAdd(&ws[slot + 2], cl);
        __threadfence();
        unsigned old = atomicAdd((unsigned*)(ws + 128), 1u);
        if (old == NBLK - 1) {
            __threadfence();
            float C = 0.f, F = 0.f, CL = 0.f;
#pragma unroll
            for (int sl = 0; sl < 8; ++sl) {
                C  += atomicAdd(&ws[sl*16 + 0], 0.f);   // coherent L2 reads
                F  += atomicAdd(&ws[sl*16 + 1], 0.f);
                CL += atomicAdd(&ws[sl*16 + 2], 0.f);
            }
            const float inv_bs = 0.25f;   // bs = 4 for every layer
            out[0] = (C + F + CL) * inv_bs;
            out[1] = C * inv_bs;
            out[2] = F * inv_bs;
            out[3] = CL * inv_bs;
        }
    }
}

extern "C" void kernel_launch(void* const* d_in, const int* in_sizes, int n_in,
                              void* d_out, int out_size, void* d_ws, size_t ws_size,
                              hipStream_t stream) {
    const float* p0  = (const float*)d_in[0];
    const float* pd0 = (const float*)d_in[1];
    const float* lb0 = (const float*)d_in[2];
    const float* bb0 = (const float*)d_in[3];
    const float* p1  = (const float*)d_in[4];
    const float* pd1 = (const float*)d_in[5];
    const float* lb1 = (const float*)d_in[6];
    const float* bb1 = (const float*)d_in[7];
    const float* p2  = (const float*)d_in[8];
    const float* pd2 = (const float*)d_in[9];
    const float* lb2 = (const float*)d_in[10];
    const float* bb2 = (const float*)d_in[11];

    float* ws = (float*)d_ws;
    hipMemsetAsync(ws, 0, 132 * sizeof(float), stream);  // 8 slots + counter

    yolo_loss_kernel<<<NBLK, 256, 0, stream>>>(
        p0, pd0, lb0, bb0, p1, pd1, lb1, bb1, p2, pd2, lb2, bb2,
        ws, (float*)d_out);
}